// Round 1
// baseline (484.874 us; speedup 1.0000x reference)
//
#include <hip/hip_runtime.h>
#include <math.h>

#define NB 15

// acc layout in d_ws: [0..14]=counts, [15..29]=sum_u, [30..44]=sum_err  (45 floats)

__global__ __launch_bounds__(256) void bin_kernel(
    const float* __restrict__ logits,
    const int* __restrict__ labels,
    float* __restrict__ acc,
    int N)
{
    __shared__ float lds[2560];          // 256 rows * 10 floats = 40 KB
    __shared__ float s_acc[3 * NB];

    const int t = threadIdx.x;
    if (t < 3 * NB) s_acc[t] = 0.0f;

    const int rowBase = blockIdx.x * 256;

    // ---- cooperative fully-coalesced staging: 640 float4 per block ----
    const long long gBaseF4 = (long long)rowBase * 10 / 4;   // blockIdx * 640
    const long long totF4   = ((long long)N * 10) / 4;
    const float4* __restrict__ src = (const float4*)logits;
    float4* dst = (float4*)lds;
#pragma unroll
    for (int k = 0; k < 3; ++k) {
        int li = t + k * 256;
        if (li < 640) {
            long long gi = gBaseF4 + li;
            if (gi < totF4) dst[li] = src[gi];
        }
    }
    __syncthreads();

    // ---- per-row compute ----
    const int row = rowBase + t;
    bool  valid = false;
    bool  err   = false;
    float u     = 0.0f;
    int   bin   = 0;
    if (row < N) {
        const float* r = lds + t * 10;
        float lv[10];
#pragma unroll
        for (int j = 0; j < 10; ++j) lv[j] = r[j];

        float m = lv[0]; int am = 0;
#pragma unroll
        for (int j = 1; j < 10; ++j) {
            if (lv[j] > m) { m = lv[j]; am = j; }
        }
        float Z = 0.0f, S = 0.0f;
#pragma unroll
        for (int j = 0; j < 10; ++j) {
            float e = exp2f((lv[j] - m) * 1.44269504088896340736f);
            Z += e;
            S += e * e;                 // sum of (unnormalized p)^2
        }
        float ratio = S / (Z * Z);      // = sum(p^2)
        u = -log2f(ratio + 1e-12f);
        valid = (u >= 0.0f) && (u < 1.0f);
        if (valid) {
            bin = (int)(u * 15.0f);     // u >= 0 so cast == floor
            if (bin > 14) bin = 14;
        }
        err = (am != labels[row]);
    }

    // ---- ballot-based wave aggregation (skewed bins -> avoid atomic serialization) ----
    const int lane = t & 63;
    float uval = valid ? u : 0.0f;
    for (int b = 0; b < NB; ++b) {
        bool inb = valid && (bin == b);
        unsigned long long mb = __ballot(inb);
        if (mb == 0ull) continue;       // wave-uniform skip of empty bins
        int cnt = __popcll(mb);
        int ec  = __popcll(__ballot(inb && err));
        float us = inb ? uval : 0.0f;
#pragma unroll
        for (int off = 32; off >= 1; off >>= 1)
            us += __shfl_xor(us, off, 64);
        if (lane == 0) {
            atomicAdd(&s_acc[b],          (float)cnt);
            atomicAdd(&s_acc[NB + b],     us);
            atomicAdd(&s_acc[2 * NB + b], (float)ec);
        }
    }
    __syncthreads();

    if (t < 3 * NB) {
        float v = s_acc[t];
        if (v != 0.0f) atomicAdd(&acc[t], v);
    }
}

__global__ void finalize_kernel(const float* __restrict__ acc,
                                float* __restrict__ out, float n)
{
    int b = threadIdx.x;
    float gap = 0.0f;
    if (b < NB) {
        float cnt = acc[b];
        if (cnt > 0.0f) {
            float u_b   = acc[NB + b] / cnt;
            float err_b = acc[2 * NB + b] / cnt;
            float inner = 2.0f * exp2f(-u_b) - 1.0f;
            if (inner < 0.0f) inner = 0.0f;
            float r_ref = 0.5f * (1.0f - sqrtf(inner));
            gap = fabsf(err_b - r_ref) * (cnt / n);
        }
    }
#pragma unroll
    for (int off = 32; off >= 1; off >>= 1)
        gap += __shfl_xor(gap, off, 64);
    if (b == 0) out[0] = gap;
}

extern "C" void kernel_launch(void* const* d_in, const int* in_sizes, int n_in,
                              void* d_out, int out_size, void* d_ws, size_t ws_size,
                              hipStream_t stream)
{
    const float* logits = (const float*)d_in[0];
    const int*   labels = (const int*)d_in[1];
    const int N = in_sizes[1];          // labels count = N rows

    float* acc = (float*)d_ws;          // 45 floats
    hipMemsetAsync(acc, 0, 3 * NB * sizeof(float), stream);

    int blocks = (N + 255) / 256;
    bin_kernel<<<blocks, 256, 0, stream>>>(logits, labels, acc, N);
    finalize_kernel<<<1, 64, 0, stream>>>(acc, (float*)d_out, (float)N);
}

// Round 2
// 248.565 us; speedup vs baseline: 1.9507x; 1.9507x over previous
//
#include <hip/hip_runtime.h>
#include <math.h>

#define NB 15

// acc layout in d_ws: [0..14]=counts, [15..29]=sum_u, [30..44]=sum_err  (45 floats)

__global__ __launch_bounds__(256, 4) void bin_kernel(
    const float* __restrict__ logits,
    const int* __restrict__ labels,
    float* __restrict__ acc,
    int N, int numTiles)
{
    __shared__ float4 lds4[2][640];       // 2 x (256 rows * 10 floats) = 20.5 KB
    __shared__ float s_acc[3 * NB];

    const int t = threadIdx.x;
    if (t < 3 * NB) s_acc[t] = 0.0f;

    // private accumulators: pk = count | (err_count<<16), su = sum of u
    int   pk[NB];
    float su[NB];
#pragma unroll
    for (int b = 0; b < NB; ++b) { pk[b] = 0; su[b] = 0.0f; }

    const float4* __restrict__ srcF4 = (const float4*)logits;
    const long long totF4 = (((long long)N * 10) + 3) >> 2;   // ceil; <=12B overread is within page
    float* ldsf = (float*)lds4;

    int tile = blockIdx.x;
    int labCur = 0;

    // ---- prologue: stage first tile into buffer 0 ----
    {
        long long base = (long long)tile * 640;
#pragma unroll
        for (int k = 0; k < 3; ++k) {
            int li = t + (k << 8);
            if (li < 640) {
                long long gi = base + li;
                float4 v = make_float4(0.f, 0.f, 0.f, 0.f);
                if (gi < totF4) v = srcF4[gi];
                lds4[0][li] = v;
            }
        }
        int row = tile * 256 + t;
        labCur = (row < N) ? labels[row] : 0;
    }
    __syncthreads();

    int cur = 0;
    while (tile < numTiles) {
        const int nxt = tile + gridDim.x;
        const bool hasNext = (nxt < numTiles);

        // ---- issue next tile's global loads into registers (latency overlap) ----
        float4 v0, v1, v2;
        int labNext = 0;
        if (hasNext) {
            long long base = (long long)nxt * 640;
            {
                long long gi = base + t;
                v0 = (gi < totF4) ? srcF4[gi] : make_float4(0.f,0.f,0.f,0.f);
            }
            {
                long long gi = base + t + 256;
                v1 = (gi < totF4) ? srcF4[gi] : make_float4(0.f,0.f,0.f,0.f);
            }
            if (t < 128) {
                long long gi = base + t + 512;
                v2 = (gi < totF4) ? srcF4[gi] : make_float4(0.f,0.f,0.f,0.f);
            }
            int row = nxt * 256 + t;
            labNext = (row < N) ? labels[row] : 0;
        }

        // ---- compute current tile from LDS ----
        {
            const float* r = ldsf + cur * 2560 + t * 10;
            const float2* r2 = (const float2*)r;
            float lv[10];
#pragma unroll
            for (int j = 0; j < 5; ++j) {
                float2 w = r2[j];
                lv[2 * j]     = w.x;
                lv[2 * j + 1] = w.y;
            }
            float m = lv[0];
#pragma unroll
            for (int j = 1; j < 10; ++j) m = fmaxf(m, lv[j]);

            const float c = 1.44269504088896340736f;
            float mc = m * c;
            float Z = 0.0f, S = 0.0f;
#pragma unroll
            for (int j = 0; j < 10; ++j) {
                float e = exp2f(fmaf(lv[j], c, -mc));
                Z += e;
                S = fmaf(e, e, S);
            }
            float ratio = S * __builtin_amdgcn_rcpf(Z * Z);   // sum(p^2), ~1ulp
            float u = -log2f(ratio + 1e-12f);

            int row = tile * 256 + t;
            bool valid = (row < N) & (u >= 0.0f) & (u < 1.0f);
            int bin = -1;
            if (valid) {
                bin = (int)(u * 15.0f);
                if (bin > 14) bin = 14;
            }
            float lvl = r[labCur];                 // dynamic LDS read: logit at label
            int e10 = (lvl != m) ? 1 : 0;          // wrong iff label isn't the (unique) max
            float uu = valid ? u : 0.0f;
            int inc = 1 + (e10 << 16);
#pragma unroll
            for (int b = 0; b < NB; ++b) {
                bool mt = (bin == b);
                pk[b] += mt ? inc : 0;
                su[b] += mt ? uu : 0.0f;
            }
        }

        // ---- write prefetched tile into other buffer, flip ----
        if (hasNext) {
            lds4[cur ^ 1][t]       = v0;
            lds4[cur ^ 1][t + 256] = v1;
            if (t < 128) lds4[cur ^ 1][t + 512] = v2;
        }
        __syncthreads();
        cur ^= 1;
        tile = nxt;
        labCur = labNext;
    }

    // ---- once-per-block reduction: wave butterfly, then shared, then global ----
    const int lane = t & 63;
#pragma unroll
    for (int b = 0; b < NB; ++b) {
        int   p = pk[b];
        float s = su[b];
#pragma unroll
        for (int off = 1; off < 64; off <<= 1) {
            p += __shfl_xor(p, off, 64);
            s += __shfl_xor(s, off, 64);
        }
        if (lane == 0) {
            atomicAdd(&s_acc[b],          (float)(p & 0xFFFF));
            atomicAdd(&s_acc[NB + b],     s);
            atomicAdd(&s_acc[2 * NB + b], (float)(p >> 16));
        }
    }
    __syncthreads();
    if (t < 3 * NB) {
        float v = s_acc[t];
        if (v != 0.0f) atomicAdd(&acc[t], v);
    }
}

__global__ void finalize_kernel(const float* __restrict__ acc,
                                float* __restrict__ out, float n)
{
    int b = threadIdx.x;
    float gap = 0.0f;
    if (b < NB) {
        float cnt = acc[b];
        if (cnt > 0.0f) {
            float u_b   = acc[NB + b] / cnt;
            float err_b = acc[2 * NB + b] / cnt;
            float inner = 2.0f * exp2f(-u_b) - 1.0f;
            if (inner < 0.0f) inner = 0.0f;
            float r_ref = 0.5f * (1.0f - sqrtf(inner));
            gap = fabsf(err_b - r_ref) * (cnt / n);
        }
    }
#pragma unroll
    for (int off = 32; off >= 1; off >>= 1)
        gap += __shfl_xor(gap, off, 64);
    if (b == 0) out[0] = gap;
}

extern "C" void kernel_launch(void* const* d_in, const int* in_sizes, int n_in,
                              void* d_out, int out_size, void* d_ws, size_t ws_size,
                              hipStream_t stream)
{
    const float* logits = (const float*)d_in[0];
    const int*   labels = (const int*)d_in[1];
    const int N = in_sizes[1];              // labels count = number of rows

    float* acc = (float*)d_ws;              // 45 floats
    hipMemsetAsync(acc, 0, 3 * NB * sizeof(float), stream);

    const int numTiles = (N + 255) / 256;
    int blocks = numTiles < 1024 ? numTiles : 1024;
    bin_kernel<<<blocks, 256, 0, stream>>>(logits, labels, acc, N, numTiles);
    finalize_kernel<<<1, 64, 0, stream>>>(acc, (float*)d_out, (float)N);
}